// Round 1
// baseline (788.280 us; speedup 1.0000x reference)
//
#include <hip/hip_runtime.h>
#include <hip/hip_bf16.h>
#include <math.h>

#define CHUNK 16
#define NN 1764
#define SORTN 2048

typedef float v2f __attribute__((ext_vector_type(2)));
typedef float v4f __attribute__((ext_vector_type(4)));

// ---------------- weight packing ----------------
// 3x3 convs: W[co][ci][3][3] -> Wpk[ci][p][20], pair p=(co>>5)*16+(co&15),
// h=(co&31)>>4 -> slot 2*k+h. One dwordx4 = 2 float2 pairs for v_pk_fma_f32.
template<int Co, int Ci>
__device__ inline void seg_pack_pk(const float* __restrict__ src, float* __restrict__ dst, int i) {
  int co = i / (Ci * 9); int rem = i - co * (Ci * 9); int ci = rem / 9; int k = rem - ci * 9;
  int p = (co >> 5) * 16 + (co & 15);
  int h = (co & 31) >> 4;
  dst[((size_t)ci * (Co >> 1) + p) * 20 + 2 * k + h] = src[i];
}
template<int Co, int CiK>
__device__ inline void seg_tr(const float* __restrict__ src, float* __restrict__ dst, int i) {
  int co = i / CiK; int cik = i - co * CiK;
  dst[cik * Co + co] = src[i];
}

__global__ void wtrans_all(
  const float* __restrict__ b1w, const float* __restrict__ c1w,
  const float* __restrict__ b2w, const float* __restrict__ c2w,
  const float* __restrict__ b3w, const float* __restrict__ b4w,
  const float* __restrict__ c3w,
  float* __restrict__ wp1b, float* __restrict__ wp1c,
  float* __restrict__ wp2b, float* __restrict__ wp2c,
  float* __restrict__ wp3b, float* __restrict__ wt4b, float* __restrict__ wt3c)
{
  int j = blockIdx.x * blockDim.x + threadIdx.x;
  if (j < 1179648) { seg_pack_pk<256, 512>(b1w, wp1b, j); return; } j -= 1179648;
  if (j < 1179648) { seg_pack_pk<256, 512>(c1w, wp1c, j); return; } j -= 1179648;
  if (j < 294912)  { seg_pack_pk<128, 256>(b2w, wp2b, j); return; } j -= 294912;
  if (j < 294912)  { seg_pack_pk<128, 256>(c2w, wp2c, j); return; } j -= 294912;
  if (j < 147456)  { seg_pack_pk<128, 128>(b3w, wp3b, j); return; } j -= 147456;
  if (j < 4608)    { seg_tr<36, 128>(b4w, wt4b, j); return; }  j -= 4608;
  if (j < 1152)    { seg_tr<9, 128>(c3w, wt3c, j); return; }
}

// ---------------- pk_fma with op_sel broadcast (R11) ----------------
// acc = w * broadcast(s.half) + acc. The neighbor scalar is consumed directly
// from the ds_read_b128 register pair; op_sel selects lo/hi half for BOTH
// output lanes -> zero splat v_movs. Same instruction & operand order as the
// previous __builtin_elementwise_fma version -> bitwise-identical arithmetic.
__device__ inline void pkfma_lo(v2f& a, v2f w, v2f s) {
  // lo_res = w.lo*s.lo + a.lo ; hi_res = w.hi*s.lo + a.hi
  asm("v_pk_fma_f32 %0, %1, %2, %0 op_sel_hi:[1,0,1]" : "+v"(a) : "v"(w), "v"(s));
}
__device__ inline void pkfma_hi(v2f& a, v2f w, v2f s) {
  // lo_res = w.lo*s.hi + a.lo ; hi_res = w.hi*s.hi + a.hi
  asm("v_pk_fma_f32 %0, %1, %2, %0 op_sel:[0,1,0] op_sel_hi:[1,1,1]" : "+v"(a) : "v"(w), "v"(s));
}
__device__ inline v2f lo2(v4f q) { return __builtin_shufflevector(q, q, 0, 1); }
__device__ inline v2f hi2(v4f q) { return __builtin_shufflevector(q, q, 2, 3); }

template<int NP>
__device__ inline void wload(v4f (&w)[NP][5], const float* __restrict__ wt,
                             int cik, int CoutH, const int (&pidx)[NP]) {
#pragma unroll
  for (int g = 0; g < NP; ++g) {
    const v4f* q = (const v4f*)(wt + ((size_t)cik * CoutH + pidx[g]) * 20);
#pragma unroll
    for (int t = 0; t < 5; ++t) w[g][t] = q[t];
  }
}

// One ci-step of the 3x3: rows pipelined (read row ky+1 during row ky FMAs).
// Accumulation order per acc[g][j] is ky->kx, identical to the R9 kernel.
template<int NP>
__device__ inline void compute_ci(v2f (&acc)[NP][14], const v4f (&w)[NP][5],
                                  const float* tbase) {
  const v4f* rq0 = (const v4f*)tbase;
  v4f ra = rq0[0], rb = rq0[1], rc = rq0[2], rd = rq0[3];
#pragma unroll
  for (int ky = 0; ky < 3; ++ky) {
    v4f na, nb_, nc, nd;
    if (ky < 2) {
      const v4f* rq = (const v4f*)(tbase + (ky + 1) * 16);
      na = rq[0]; nb_ = rq[1]; nc = rq[2]; nd = rq[3];
    }
    v2f rp[8] = {lo2(ra), hi2(ra), lo2(rb), hi2(rb), lo2(rc), hi2(rc), lo2(rd), hi2(rd)};
#pragma unroll
    for (int kx = 0; kx < 3; ++kx) {
      const int kk = ky * 3 + kx;
#pragma unroll
      for (int g = 0; g < NP; ++g) {
        v2f wv = (kk & 1) ? hi2(w[g][kk >> 1]) : lo2(w[g][kk >> 1]);
#pragma unroll
        for (int j = 0; j < 14; ++j) {
          const int idx = j + kx;
          if (idx & 1) pkfma_hi(acc[g][j], wv, rp[idx >> 1]);
          else         pkfma_lo(acc[g][j], wv, rp[idx >> 1]);
        }
      }
    }
    if (ky < 2) { ra = na; rb = nb_; rc = nc; rd = nd; }
  }
}

// ---------------- split-K partial conv3x3 (LDS tile + v_pk_fma_f32) ----------------
// NOTE (R10 post-mortem): MFMA/bf16x3 conv is precision-blocked here — scores cluster
// at the 0.5 validity threshold; ~1e-5 logit error flips NMS decisions. Keep fp32.
// R11: register double-buffered weight prefetch (wA/wB ping-pong, distance-1 ci,
// carried across the lcb barrier) + op_sel-broadcast pk_fma + pipelined LDS rows.
// Theory: 92-VGPR build had zero staging room -> exposed L2 (~300cy) + LDS (~120cy)
// latency every ci with only ~2 waves/SIMD to cover it (VALUBusy 66%).
template<int COPT>
__global__ __launch_bounds__(256, 2) void conv3x3_part(
    const float* __restrict__ in0, const float* __restrict__ in1,
    const float* __restrict__ wt0, const float* __restrict__ wt1,
    float* __restrict__ po0, float* __restrict__ po1,
    int Cin, int Cout, int cobPerHead, int cinPerSplit, size_t sStride)
{
  constexpr int NP = COPT / 2;
  const int tid = threadIdx.x;
  const int bx  = blockIdx.x;
  const int b   = blockIdx.y;
  const int s   = blockIdx.z;
  const int head = bx / cobPerHead;
  const int cob  = bx - head * cobPerHead;
  const float* in  = head ? in1  : in0;
  const float* wt  = head ? wt1  : wt0;
  float* po        = head ? po1  : po0;
  const int co0 = cob * (16 * COPT);

  const int col = tid & 15;
  const int r   = tid >> 4;
  const bool ract = r < 14;

  __shared__ float tile[2][CHUNK][16][16];

  {
    float* tz = &tile[0][0][0][0];
    for (int i = tid; i < 2 * CHUNK * 256; i += 256) tz[i] = 0.0f;
  }
  __syncthreads();

  const int p = tid;
  const bool pa = p < 196;
  const int prow = p / 14, pcol = p - prow * 14;
  const float* inb = in + (size_t)b * Cin * 196;
  const int cb0 = (s * cinPerSplit) / CHUNK;
  const int nch = cinPerSplit / CHUNK;
  const int CoutH = Cout >> 1;

  int pidx[NP];
#pragma unroll
  for (int g = 0; g < NP; ++g) pidx[g] = ((co0 >> 5) + g) * 16 + col;

  // issue first weight prefetch before the tile fill so both drain at the barrier
  v4f wA[NP][5], wB[NP][5];
  if (ract) wload<NP>(wA, wt, cb0 * CHUNK, CoutH, pidx);

  if (pa) {
#pragma unroll
    for (int ci = 0; ci < CHUNK; ++ci)
      tile[0][ci][prow + 1][pcol + 1] = inb[(cb0 * CHUNK + ci) * 196 + p];
  }
  __syncthreads();

  v2f acc[NP][14];
#pragma unroll
  for (int g = 0; g < NP; ++g)
#pragma unroll
    for (int j = 0; j < 14; ++j) acc[g][j] = (v2f)(0.0f);

  for (int lcb = 0; lcb < nch; ++lcb) {
    const int cbg = cb0 + lcb;
    const int cur = lcb & 1;
    const bool more = (lcb + 1 < nch);
    float v[CHUNK];
    if (more && pa) {
#pragma unroll
      for (int ci = 0; ci < CHUNK; ++ci)
        v[ci] = inb[((cbg + 1) * CHUNK + ci) * 196 + p];
    }
    if (ract) {
      const int base = cbg * CHUNK;
      const float* tb0 = &tile[cur][0][r][0];
      for (int ci = 0; ci < CHUNK; ci += 2) {
        wload<NP>(wB, wt, base + ci + 1, CoutH, pidx);
        compute_ci<NP>(acc, wA, tb0 + ci * 256);
        // ci+2==CHUNK rolls into next lcb's first chunk (contiguous cik stream);
        // issuing before the barrier lets the mandatory vmcnt drain absorb it.
        if (ci + 2 < CHUNK || more) wload<NP>(wA, wt, base + ci + 2, CoutH, pidx);
        compute_ci<NP>(acc, wB, tb0 + ci * 256 + 256);
      }
    }
    if (more && pa) {
#pragma unroll
      for (int ci = 0; ci < CHUNK; ++ci)
        tile[1 - cur][ci][prow + 1][pcol + 1] = v[ci];
    }
    __syncthreads();
  }

  if (ract) {
#pragma unroll
    for (int g = 0; g < NP; ++g) {
      const int ocx = 32 * g + col;
      const int ocy = ocx + 16;
      float* opx = po + (size_t)s * sStride + ((size_t)b * Cout + co0 + ocx) * 196 + r * 14;
      float* opy = po + (size_t)s * sStride + ((size_t)b * Cout + co0 + ocy) * 196 + r * 14;
#pragma unroll
      for (int j = 0; j < 14; ++j) { opx[j] = acc[g][j].x; opy[j] = acc[g][j].y; }
    }
  }
}

// ---------------- combine partials + bias + GELU + GroupNorm(8ch groups) ----------------
template<int S>
__global__ __launch_bounds__(256) void combine_gn(
    const float* __restrict__ po0, const float* __restrict__ po1,
    const float* __restrict__ bs0, const float* __restrict__ bs1,
    const float* __restrict__ gw0, const float* __restrict__ gw1,
    const float* __restrict__ gb0, const float* __restrict__ gb1,
    float* __restrict__ out0, float* __restrict__ out1,
    int Cout, int cobPerHead, size_t sStride)
{
  const int tid = threadIdx.x, bx = blockIdx.x, b = blockIdx.y;
  const int head = bx / cobPerHead, cob = bx - head * cobPerHead;
  const float* po = head ? po1 : po0;
  const float* bs = head ? bs1 : bs0;
  const float* gw = head ? gw1 : gw0;
  const float* gb = head ? gb1 : gb0;
  float* out      = head ? out1 : out0;
  const int co0 = cob * 16;

  __shared__ float red[4][4];
  __shared__ float stats[4];

  const int p = tid;
  const bool pa = p < 196;
  float v[16];
  float s0 = 0.f, q0 = 0.f, s1 = 0.f, q1 = 0.f;
  if (pa) {
#pragma unroll
    for (int c = 0; c < 16; ++c) {
      const size_t base = ((size_t)b * Cout + co0 + c) * 196 + p;
      float x = bs[co0 + c];
#pragma unroll
      for (int s = 0; s < S; ++s) x += po[base + (size_t)s * sStride];
      float g = 0.5f * x * (1.0f + erff(x * 0.70710678118654752440f));
      v[c] = g;
      if (c < 8) { s0 += g; q0 += g * g; } else { s1 += g; q1 += g * g; }
    }
  }
#pragma unroll
  for (int off = 32; off > 0; off >>= 1) {
    s0 += __shfl_down(s0, off, 64); q0 += __shfl_down(q0, off, 64);
    s1 += __shfl_down(s1, off, 64); q1 += __shfl_down(q1, off, 64);
  }
  const int wave = tid >> 6, lane = tid & 63;
  if (lane == 0) { red[wave][0] = s0; red[wave][1] = q0; red[wave][2] = s1; red[wave][3] = q1; }
  __syncthreads();
  if (tid == 0) {
    float S0 = red[0][0] + red[1][0] + red[2][0] + red[3][0];
    float Q0 = red[0][1] + red[1][1] + red[2][1] + red[3][1];
    float S1 = red[0][2] + red[1][2] + red[2][2] + red[3][2];
    float Q1 = red[0][3] + red[1][3] + red[2][3] + red[3][3];
    float m0 = S0 * (1.0f / 1568.0f);
    float v0 = Q0 * (1.0f / 1568.0f) - m0 * m0;
    float m1 = S1 * (1.0f / 1568.0f);
    float v1 = Q1 * (1.0f / 1568.0f) - m1 * m1;
    stats[0] = m0; stats[1] = 1.0f / sqrtf(v0 + 1e-5f);
    stats[2] = m1; stats[3] = 1.0f / sqrtf(v1 + 1e-5f);
  }
  __syncthreads();
  if (pa) {
    float m0 = stats[0], i0 = stats[1], m1 = stats[2], i1 = stats[3];
#pragma unroll
    for (int c = 0; c < 16; ++c) {
      float m  = (c < 8) ? m0 : m1;
      float iv = (c < 8) ? i0 : i1;
      float y = (v[c] - m) * iv * gw[co0 + c] + gb[co0 + c];
      out[((size_t)b * Cout + co0 + c) * 196 + p] = y;
    }
  }
}

// ---------------- 1x1 heads, re-gridded: (b, og) blocks; og 0-3 = bbox 9-out chunks, og 4 = conf ----------------
__global__ __launch_bounds__(256) void heads_1x1(
    const float* __restrict__ tb, const float* __restrict__ tc,
    const float* __restrict__ wtb, const float* __restrict__ wtc, // [128][36], [128][9]
    const float* __restrict__ bb,  const float* __restrict__ bc,
    float* __restrict__ bbox, float* __restrict__ conf)
{
  const int b = blockIdx.x, og = blockIdx.y, tid = threadIdx.x;
  if (tid >= 196) return;
  const int p = tid;
  const bool isConf = (og == 4);
  const float* in = isConf ? tc : tb;
  const float* wbase = isConf ? wtc : (wtb + og * 9);
  const int wstride = isConf ? 9 : 36;
  const float* bsrc = isConf ? bc : (bb + og * 9);

  float a[9];
#pragma unroll
  for (int o = 0; o < 9; ++o) a[o] = bsrc[o];
  const float* pin = in + (size_t)b * 128 * 196 + p;
  for (int ci = 0; ci < 128; ++ci) {
    float x = pin[ci * 196];
    const float* w = wbase + ci * wstride;   // uniform -> s_load
#pragma unroll
    for (int o = 0; o < 9; ++o) a[o] = fmaf(w[o], x, a[o]);
  }
  if (isConf) {
    float* cf = conf + (size_t)b * NN + (size_t)p * 9;
#pragma unroll
    for (int o = 0; o < 9; ++o) cf[o] = 1.0f / (1.0f + expf(-a[o]));
  } else {
    float* bp = bbox + ((size_t)b * NN) * 4 + (size_t)p * 36 + og * 9;
#pragma unroll
    for (int o = 0; o < 9; ++o) bp[o] = a[o];
  }
}

// ---------------- per-image greedy NMS, 512 threads ----------------
__global__ __launch_bounds__(512) void nms_kernel(
  const float* __restrict__ bbox, const float* __restrict__ conf, float* __restrict__ out)
{
  const int b = blockIdx.x, tid = threadIdx.x;
  __shared__ unsigned long long key[SORTN];
  __shared__ float sx1[NN], sy1[NN], sx2[NN], sy2[NN], sar[NN], ssc[NN];
  __shared__ unsigned char sup[NN];
  __shared__ int sV, sMin;

  if (tid == 0) sV = 0;
  __syncthreads();
  int cntv = 0;
  const float* cf = conf + (size_t)b * NN;
  for (int i = tid; i < SORTN; i += 512) {
    unsigned long long k;
    if (i < NN) {
      float s = cf[i];
      unsigned rank = (unsigned)(NN - 1 - i);
      if (s > 0.5f) { k = (((unsigned long long)__float_as_uint(s)) << 32) | rank; cntv++; }
      else k = (unsigned long long)rank;
    } else k = 0ull;
    key[i] = k;
  }
  atomicAdd(&sV, cntv);
  __syncthreads();
  const int V = sV;

  for (int kk = 2; kk <= SORTN; kk <<= 1) {
    for (int j = kk >> 1; j > 0; j >>= 1) {
      for (int i = tid; i < SORTN; i += 512) {
        int ixj = i ^ j;
        if (ixj > i) {
          unsigned long long a = key[i], c = key[ixj];
          bool dirDesc = ((i & kk) == 0);
          if ((a < c) == dirDesc) { key[i] = c; key[ixj] = a; }
        }
      }
      __syncthreads();
    }
  }

  const float* bbb = bbox + (size_t)b * NN * 4;
  for (int i = tid; i < V; i += 512) {
    unsigned long long k = key[i];
    int idx = NN - 1 - (int)(unsigned)(k & 0xFFFFFFFFull);
    float s = __uint_as_float((unsigned)(k >> 32));
    const float* bp = bbb + (size_t)idx * 4;
    float x1 = fminf(fmaxf(bp[0], 0.0f), 1.0f);
    float y1 = fminf(fmaxf(bp[1], 0.0f), 1.0f);
    float x2 = fminf(fmaxf(bp[2], 0.0f), 1.0f);
    float y2 = fminf(fmaxf(bp[3], 0.0f), 1.0f);
    sx1[i] = x1; sy1[i] = y1; sx2[i] = x2; sy2[i] = y2;
    sar[i] = (x2 - x1) * (y2 - y1);
    ssc[i] = s;
    sup[i] = 0;
  }
  __syncthreads();

  int kept = 0, cur = 0;
  float* ob = out + (size_t)b * 50 * 5;
  while (kept < 50 && cur < V) {
    int nxt = -1;
    for (int base = cur; base < V; base += 512) {
      if (tid == 0) sMin = 0x7FFFFFFF;
      __syncthreads();
      int i = base + tid;
      if (i < V && !sup[i]) atomicMin(&sMin, i);
      __syncthreads();
      if (sMin != 0x7FFFFFFF) { nxt = sMin; break; }
    }
    if (nxt < 0) break;
    float kx1 = sx1[nxt], ky1 = sy1[nxt], kx2 = sx2[nxt], ky2 = sy2[nxt], ka = sar[nxt];
    if (tid == 0) {
      float* rr = ob + kept * 5;
      rr[0] = kx1; rr[1] = ky1; rr[2] = kx2; rr[3] = ky2; rr[4] = ssc[nxt];
    }
    kept++;
    for (int jj = nxt + 1 + tid; jj < V; jj += 512) {
      if (!sup[jj]) {
        float xx1 = fmaxf(kx1, sx1[jj]);
        float yy1 = fmaxf(ky1, sy1[jj]);
        float xx2 = fminf(kx2, sx2[jj]);
        float yy2 = fminf(ky2, sy2[jj]);
        float inter = fmaxf(xx2 - xx1, 0.0f) * fmaxf(yy2 - yy1, 0.0f);
        float iou = inter / ((ka + sar[jj]) - inter);
        if (!(iou < 0.3f)) sup[jj] = 1;
      }
    }
    cur = nxt + 1;
    __syncthreads();
  }
  for (int rr = kept + tid; rr < 50; rr += 512) {
    float* qq = ob + rr * 5;
    qq[0] = 0.0f; qq[1] = 0.0f; qq[2] = 0.0f; qq[3] = 0.0f; qq[4] = -1.0f;
  }
}

// ---------------- launch ----------------
extern "C" void kernel_launch(void* const* d_in, const int* in_sizes, int n_in,
                              void* d_out, int out_size, void* d_ws, size_t ws_size,
                              hipStream_t stream)
{
  const float* features = (const float*)d_in[0];
  const float* b1w = (const float*)d_in[1];  const float* b1b = (const float*)d_in[2];
  const float* bg1w = (const float*)d_in[3]; const float* bg1b = (const float*)d_in[4];
  const float* b2w = (const float*)d_in[5];  const float* b2b = (const float*)d_in[6];
  const float* bg2w = (const float*)d_in[7]; const float* bg2b = (const float*)d_in[8];
  const float* b3w = (const float*)d_in[9];  const float* b3b = (const float*)d_in[10];
  const float* bg3w = (const float*)d_in[11]; const float* bg3b = (const float*)d_in[12];
  const float* b4w = (const float*)d_in[13]; const float* b4b = (const float*)d_in[14];
  const float* c1w = (const float*)d_in[15]; const float* c1b = (const float*)d_in[16];
  const float* cg1w = (const float*)d_in[17]; const float* cg1b = (const float*)d_in[18];
  const float* c2w = (const float*)d_in[19]; const float* c2b = (const float*)d_in[20];
  const float* cg2w = (const float*)d_in[21]; const float* cg2b = (const float*)d_in[22];
  const float* c3w = (const float*)d_in[23]; const float* c3b = (const float*)d_in[24];

  float* ws = (float*)d_ws;
  float* wp1b = ws; ws += 1310720;   // 512*128*20
  float* wp1c = ws; ws += 1310720;
  float* wp2b = ws; ws += 327680;    // 256*64*20
  float* wp2c = ws; ws += 327680;
  float* wp3b = ws; ws += 163840;    // 128*64*20
  float* wt4b = ws; ws += 4608;
  float* wt3c = ws; ws += 1152;
  float* t1b = ws; ws += 1605632;    // 32*256*196
  float* t1c = ws; ws += 1605632;
  float* t2b = ws; ws += 802816;     // 32*128*196
  float* t2c = ws; ws += 802816;
  float* P   = ws; ws += 12845056;   // partial region, aliased across layers
  float* bbox = ws; ws += 225792;
  float* conf = ws; ws += 56448;
  float* t3b = t1b;                  // alias: t1b dead after conv2 reads it

  wtrans_all<<<12119, 256, 0, stream>>>(b1w, c1w, b2w, c2w, b3w, b4w, c3w,
                                        wp1b, wp1c, wp2b, wp2c, wp3b, wt4b, wt3c);

  // conv1: Cin=512, Cout=256, COPT=4 (64 co/block), S=4 -> 1024 blocks
  {
    const size_t sStr = (size_t)32 * 256 * 196;          // 1605632
    conv3x3_part<4><<<dim3(8, 32, 4), 256, 0, stream>>>(
        features, features, wp1b, wp1c, P, P + 4 * sStr, 512, 256, 4, 128, sStr);
    combine_gn<4><<<dim3(32, 32), 256, 0, stream>>>(
        P, P + 4 * sStr, b1b, c1b, bg1w, cg1w, bg1b, cg1b, t1b, t1c, 256, 16, sStr);
  }
  // conv2: Cin=256, Cout=128, COPT=4, S=8 -> 1024 blocks
  {
    const size_t sStr = (size_t)32 * 128 * 196;          // 802816
    conv3x3_part<4><<<dim3(4, 32, 8), 256, 0, stream>>>(
        t1b, t1c, wp2b, wp2c, P, P + 8 * sStr, 256, 128, 2, 32, sStr);
    combine_gn<8><<<dim3(16, 32), 256, 0, stream>>>(
        P, P + 8 * sStr, b2b, c2b, bg2w, cg2w, bg2b, cg2b, t2b, t2c, 128, 8, sStr);
  }
  // conv3 (bbox only): Cin=128, Cout=128, COPT=2, S=8 -> 1024 blocks
  {
    const size_t sStr = (size_t)32 * 128 * 196;
    conv3x3_part<2><<<dim3(4, 32, 8), 256, 0, stream>>>(
        t2b, t2b, wp3b, wp3b, P, P, 128, 128, 4, 16, sStr);
    combine_gn<8><<<dim3(8, 32), 256, 0, stream>>>(
        P, P, b3b, b3b, bg3w, bg3w, bg3b, bg3b, t3b, t3b, 128, 8, sStr);
  }

  heads_1x1<<<dim3(32, 5), 256, 0, stream>>>(t3b, t2c, wt4b, wt3c, b4b, c3b, bbox, conf);
  nms_kernel<<<32, 512, 0, stream>>>(bbox, conf, (float*)d_out);
}